// Round 1
// baseline (1568.011 us; speedup 1.0000x reference)
//
#include <hip/hip_runtime.h>
#include <hip/hip_bf16.h>
#include <math.h>

// Problem constants: B=8, C=512, H=W=32 (N=1024), G=8, D=128, Cg=64
#define EPSF 1e-5f
constexpr int QKV_STRIDE = 8 * 8 * 128 * 1024;  // one of q/k/v: [B,G,D,N] floats

__device__ __forceinline__ float gelu_exact(float x) {
    return 0.5f * x * (1.0f + erff(x * 0.70710678118654752f));
}

// ---------------------------------------------------------------------------
// Kernel A: grouped 1x1 conv (qkv projection) + BN(eval) + exact GELU
// grid (8 n-tiles, 64 bg, 3 proj), block 256 (16x16), tile 128d x 128n, K=64
// ---------------------------------------------------------------------------
__global__ __launch_bounds__(256) void qkv_proj(
    const float* __restrict__ x,
    const float* __restrict__ wq, const float* __restrict__ bq, const float* __restrict__ nq,
    const float* __restrict__ wk, const float* __restrict__ bk, const float* __restrict__ nk,
    const float* __restrict__ wv, const float* __restrict__ bv, const float* __restrict__ nv,
    float* __restrict__ qkv)
{
    __shared__ float ws_t[32][132];   // transposed weight tile [c][d], padded pitch
    __shared__ float xs[32][128];     // x tile [c][n]

    const int t  = threadIdx.x;
    const int tx = t & 15, ty = t >> 4;
    const int n0 = blockIdx.x * 128;
    const int bg = blockIdx.y;
    const int b  = bg >> 3, g = bg & 7;
    const int z  = blockIdx.z;

    const float* w  = (z == 0) ? wq : (z == 1) ? wk : wv;
    const float* bs = (z == 0) ? bq : (z == 1) ? bk : bv;
    const float* bn = (z == 0) ? nq : (z == 1) ? nk : nv;

    float acc[8][8];
    #pragma unroll
    for (int r = 0; r < 8; ++r)
        #pragma unroll
        for (int jj = 0; jj < 8; ++jj) acc[r][jj] = 0.0f;

    const float* xbase = x + (size_t)(b * 512 + g * 64) * 1024 + n0;
    const float* wbase = w + g * (128 * 64);

    for (int kb = 0; kb < 64; kb += 32) {
        __syncthreads();
        // load w tile transposed: 128 d x 32 c
        #pragma unroll
        for (int it = 0; it < 16; ++it) {
            int idx = it * 256 + t;
            int cl = idx & 31, d = idx >> 5;
            ws_t[cl][d] = wbase[d * 64 + kb + cl];
        }
        // load x tile: 32 c x 128 n
        #pragma unroll
        for (int it = 0; it < 16; ++it) {
            int idx = it * 256 + t;
            int nl = idx & 127, cl = idx >> 7;
            xs[cl][nl] = xbase[(size_t)(kb + cl) * 1024 + nl];
        }
        __syncthreads();
        #pragma unroll
        for (int k = 0; k < 32; ++k) {
            float a[8], bb[8];
            *(float4*)&a[0]  = *(const float4*)&ws_t[k][8 * ty];
            *(float4*)&a[4]  = *(const float4*)&ws_t[k][8 * ty + 4];
            *(float4*)&bb[0] = *(const float4*)&xs[k][8 * tx];
            *(float4*)&bb[4] = *(const float4*)&xs[k][8 * tx + 4];
            #pragma unroll
            for (int r = 0; r < 8; ++r)
                #pragma unroll
                for (int jj = 0; jj < 8; ++jj)
                    acc[r][jj] = fmaf(a[r], bb[jj], acc[r][jj]);
        }
    }

    // epilogue: bias + BN + GELU, store to qkv[z]
    float* obase = qkv + (size_t)z * QKV_STRIDE + (size_t)(bg * 128) * 1024 + n0;
    const float* bng = bn + g * 128;
    #pragma unroll
    for (int r = 0; r < 8; ++r) {
        int d = 8 * ty + r;
        float gamma = bng[d];
        float beta  = bng[1024 + d];
        float mean  = bng[2048 + d];
        float var   = bng[3072 + d];
        float sc  = gamma * rsqrtf(var + EPSF);
        float off = (bs[g * 128 + d] - mean) * sc + beta;
        float o[8];
        #pragma unroll
        for (int jj = 0; jj < 8; ++jj)
            o[jj] = gelu_exact(fmaf(acc[r][jj], sc, off));
        *(float4*)&obase[(size_t)d * 1024 + 8 * tx]     = *(float4*)&o[0];
        *(float4*)&obase[(size_t)d * 1024 + 8 * tx + 4] = *(float4*)&o[4];
    }
}

// ---------------------------------------------------------------------------
// Kernel B: flash attention per (b,g).  q,k,v: [128][1024] each (fp32).
// Block: 256 thr, 32 queries, key tiles of 64, online softmax.
// Thread map: i = t>>5 (q-group of 4), j = t&31 (m-group of 2 / d lane).
// LDS: qs[128][32] | ks[64][64] | ps[32][68] | vs[32][68]  = 49 KB
// ---------------------------------------------------------------------------
__global__ __launch_bounds__(256) void attn_flash(
    const float* __restrict__ qkv, float* __restrict__ go)
{
    __shared__ float smem[12544];
    float* qs = smem;               // [128][32]
    float* ks = smem + 4096;        // [64][64]
    float* ps = smem + 8192;        // [32][68]
    float* vs = smem + 8192 + 2176; // [32][68]

    const int t = threadIdx.x;
    const int j = t & 31, i = t >> 5;
    const int q0 = blockIdx.x * 32;
    const int bg = blockIdx.y;
    const float scale = 0.08838834764831845f;  // D^-0.5

    const float* qg = qkv + (size_t)(bg * 128) * 1024;
    const float* kg = qkv + QKV_STRIDE + (size_t)(bg * 128) * 1024;
    const float* vg = qkv + 2 * (size_t)QKV_STRIDE + (size_t)(bg * 128) * 1024;

    // load q tile (pre-scaled)
    {
        int ql = t & 31, db = t >> 5;
        #pragma unroll
        for (int it = 0; it < 16; ++it) {
            int d = it * 8 + db;
            qs[d * 32 + ql] = qg[(size_t)d * 1024 + q0 + ql] * scale;
        }
    }

    float mrun[4], lrun[4], O[4][4];
    #pragma unroll
    for (int r = 0; r < 4; ++r) {
        mrun[r] = -INFINITY; lrun[r] = 0.0f;
        #pragma unroll
        for (int c = 0; c < 4; ++c) O[r][c] = 0.0f;
    }

    for (int kt = 0; kt < 16; ++kt) {
        const int m0 = kt * 64;
        float S[4][2] = {{0.f,0.f},{0.f,0.f},{0.f,0.f},{0.f,0.f}};

        // ---- S = q^T k, d chunked by 64 ----
        for (int c = 0; c < 2; ++c) {
            __syncthreads();   // WAR on ks (and makes qs visible on first pass)
            {
                int ml = t & 63, dlb = t >> 6;
                #pragma unroll
                for (int it = 0; it < 16; ++it) {
                    int dl = it * 4 + dlb;
                    ks[dl * 64 + ml] = kg[(size_t)(64 * c + dl) * 1024 + m0 + ml];
                }
            }
            __syncthreads();   // ks ready
            #pragma unroll 16
            for (int dd = 0; dd < 64; ++dd) {
                const float4 a  = *(const float4*)&qs[(64 * c + dd) * 32 + 4 * i];
                const float2 kk = *(const float2*)&ks[dd * 64 + 2 * j];
                S[0][0] = fmaf(a.x, kk.x, S[0][0]); S[0][1] = fmaf(a.x, kk.y, S[0][1]);
                S[1][0] = fmaf(a.y, kk.x, S[1][0]); S[1][1] = fmaf(a.y, kk.y, S[1][1]);
                S[2][0] = fmaf(a.z, kk.x, S[2][0]); S[2][1] = fmaf(a.z, kk.y, S[2][1]);
                S[3][0] = fmaf(a.w, kk.x, S[3][0]); S[3][1] = fmaf(a.w, kk.y, S[3][1]);
            }
        }

        // ---- online softmax over the 32 lanes of each q-row group ----
        #pragma unroll
        for (int r = 0; r < 4; ++r) {
            float tm = fmaxf(S[r][0], S[r][1]);
            #pragma unroll
            for (int off = 1; off < 32; off <<= 1)
                tm = fmaxf(tm, __shfl_xor(tm, off));
            float nm = fmaxf(mrun[r], tm);
            float rf = expf(mrun[r] - nm);
            float p0 = expf(S[r][0] - nm);
            float p1 = expf(S[r][1] - nm);
            float ts = p0 + p1;
            #pragma unroll
            for (int off = 1; off < 32; off <<= 1)
                ts += __shfl_xor(ts, off);
            lrun[r] = lrun[r] * rf + ts;
            mrun[r] = nm;
            O[r][0] *= rf; O[r][1] *= rf; O[r][2] *= rf; O[r][3] *= rf;
            S[r][0] = p0; S[r][1] = p1;   // S now holds P
        }

        // write P tile to LDS
        #pragma unroll
        for (int r = 0; r < 4; ++r) {
            ps[(4 * i + r) * 68 + 2 * j]     = S[r][0];
            ps[(4 * i + r) * 68 + 2 * j + 1] = S[r][1];
        }

        // ---- O += P * V^T, v d-chunked by 32; thread owns d = 32c + j ----
        for (int c = 0; c < 4; ++c) {
            __syncthreads();   // WAR on vs; also publishes ps on c==0
            {
                int ml = t & 63, dlb = t >> 6;
                #pragma unroll
                for (int it = 0; it < 8; ++it) {
                    int dl = it * 4 + dlb;
                    vs[dl * 68 + ml] = vg[(size_t)(32 * c + dl) * 1024 + m0 + ml];
                }
            }
            __syncthreads();   // vs ready
            #pragma unroll
            for (int mm = 0; mm < 16; ++mm) {
                const float4 v4 = *(const float4*)&vs[j * 68 + 4 * mm];
                #pragma unroll
                for (int r = 0; r < 4; ++r) {
                    const float4 p4 = *(const float4*)&ps[(4 * i + r) * 68 + 4 * mm];
                    O[r][c] += p4.x * v4.x + p4.y * v4.y + p4.z * v4.z + p4.w * v4.w;
                }
            }
        }
    }

    // ---- normalize, transpose via LDS, coalesced store to go [B,1024,N] ----
    __syncthreads();
    float* ot = smem;  // [128][33] overlaps dead qs/ks
    #pragma unroll
    for (int r = 0; r < 4; ++r) {
        float inv = 1.0f / lrun[r];
        #pragma unroll
        for (int c = 0; c < 4; ++c)
            ot[(32 * c + j) * 33 + 4 * i + r] = O[r][c] * inv;
    }
    __syncthreads();
    {
        int ql = t & 31, db = t >> 5;
        float* gob = go + (size_t)(bg * 128) * 1024 + q0;
        #pragma unroll
        for (int it = 0; it < 16; ++it) {
            int d = it * 8 + db;
            gob[(size_t)d * 1024 + ql] = ot[d * 33 + ql];
        }
    }
}

// ---------------------------------------------------------------------------
// Kernel C: fusion 1x1 conv (1024 -> 512) + BN(eval) + GELU -> d_out (pre-LN)
// grid (8 n-tiles, 8 co-tiles, 8 b), block 256 (16x16), tile 64co x 128n, K=1024
// ---------------------------------------------------------------------------
__global__ __launch_bounds__(256) void fusion_gemm(
    const float* __restrict__ go, const float* __restrict__ wf,
    const float* __restrict__ bf, const float* __restrict__ bnf,
    float* __restrict__ y)
{
    __shared__ float wt[32][68];    // transposed w tile [ci][co]
    __shared__ float gs[32][128];   // go tile [ci][n]

    const int t  = threadIdx.x;
    const int tx = t & 15, ty = t >> 4;
    const int n0  = blockIdx.x * 128;
    const int co0 = blockIdx.y * 64;
    const int b   = blockIdx.z;

    float acc[4][8];
    #pragma unroll
    for (int r = 0; r < 4; ++r)
        #pragma unroll
        for (int jj = 0; jj < 8; ++jj) acc[r][jj] = 0.0f;

    const float* gob = go + (size_t)b * 1024 * 1024 + n0;

    for (int kb = 0; kb < 1024; kb += 32) {
        __syncthreads();
        #pragma unroll
        for (int it = 0; it < 8; ++it) {   // w: 64 co x 32 ci
            int idx = it * 256 + t;
            int cl = idx & 31, cc = idx >> 5;
            wt[cl][cc] = wf[(size_t)(co0 + cc) * 1024 + kb + cl];
        }
        #pragma unroll
        for (int it = 0; it < 16; ++it) {  // go: 32 ci x 128 n
            int idx = it * 256 + t;
            int nl = idx & 127, kl = idx >> 7;
            gs[kl][nl] = gob[(size_t)(kb + kl) * 1024 + nl];
        }
        __syncthreads();
        #pragma unroll
        for (int k = 0; k < 32; ++k) {
            float a4[4], b8[8];
            *(float4*)&a4[0] = *(const float4*)&wt[k][4 * ty];
            *(float4*)&b8[0] = *(const float4*)&gs[k][8 * tx];
            *(float4*)&b8[4] = *(const float4*)&gs[k][8 * tx + 4];
            #pragma unroll
            for (int r = 0; r < 4; ++r)
                #pragma unroll
                for (int jj = 0; jj < 8; ++jj)
                    acc[r][jj] = fmaf(a4[r], b8[jj], acc[r][jj]);
        }
    }

    float* yb = y + (size_t)(b * 512) * 1024 + n0;
    #pragma unroll
    for (int r = 0; r < 4; ++r) {
        int co = co0 + 4 * ty + r;
        float gamma = bnf[co];
        float beta  = bnf[512 + co];
        float mean  = bnf[1024 + co];
        float var   = bnf[1536 + co];
        float sc  = gamma * rsqrtf(var + EPSF);
        float off = (bf[co] - mean) * sc + beta;
        float o[8];
        #pragma unroll
        for (int jj = 0; jj < 8; ++jj)
            o[jj] = gelu_exact(fmaf(acc[r][jj], sc, off));
        *(float4*)&yb[(size_t)co * 1024 + 8 * tx]     = *(float4*)&o[0];
        *(float4*)&yb[(size_t)co * 1024 + 8 * tx + 4] = *(float4*)&o[4];
    }
}

// ---------------------------------------------------------------------------
// Kernel D: LayerNorm over channel dim, in-place on d_out.
// Block 256 = 4 c-groups x 64 columns; grid (16 col-tiles, 8 b)
// ---------------------------------------------------------------------------
__global__ __launch_bounds__(256) void layernorm_cw(
    float* __restrict__ y, const float* __restrict__ lng, const float* __restrict__ lnb)
{
    __shared__ float s1[4][64];
    __shared__ float s2[4][64];
    const int t = threadIdx.x;
    const int cl = t & 63, cg = t >> 6;
    const int col = blockIdx.x * 64 + cl;
    const int b   = blockIdx.y;
    float* yb = y + (size_t)b * 512 * 1024 + col;

    float sum = 0.0f, sq = 0.0f;
    for (int c = cg * 128; c < cg * 128 + 128; ++c) {
        float v = yb[(size_t)c * 1024];
        sum += v; sq = fmaf(v, v, sq);
    }
    s1[cg][cl] = sum; s2[cg][cl] = sq;
    __syncthreads();
    float st = s1[0][cl] + s1[1][cl] + s1[2][cl] + s1[3][cl];
    float qt = s2[0][cl] + s2[1][cl] + s2[2][cl] + s2[3][cl];
    float mean = st * (1.0f / 512.0f);
    float var  = qt * (1.0f / 512.0f) - mean * mean;
    float rstd = rsqrtf(var + EPSF);
    for (int c = cg * 128; c < cg * 128 + 128; ++c) {
        float v = yb[(size_t)c * 1024];
        yb[(size_t)c * 1024] = (v - mean) * rstd * lng[c] + lnb[c];
    }
}

// ---------------------------------------------------------------------------
extern "C" void kernel_launch(void* const* d_in, const int* in_sizes, int n_in,
                              void* d_out, int out_size, void* d_ws, size_t ws_size,
                              hipStream_t stream) {
    const float* x   = (const float*)d_in[0];
    const float* wq  = (const float*)d_in[1];
    const float* bq  = (const float*)d_in[2];
    const float* nq  = (const float*)d_in[3];
    const float* wk  = (const float*)d_in[4];
    const float* bk  = (const float*)d_in[5];
    const float* nk  = (const float*)d_in[6];
    const float* wv  = (const float*)d_in[7];
    const float* bv  = (const float*)d_in[8];
    const float* nv  = (const float*)d_in[9];
    const float* wf  = (const float*)d_in[10];
    const float* bf  = (const float*)d_in[11];
    const float* nf  = (const float*)d_in[12];
    const float* lng = (const float*)d_in[13];
    const float* lnb = (const float*)d_in[14];

    float* qkv = (float*)d_ws;                    // 3 * QKV_STRIDE floats
    float* go  = (float*)d_ws + 3 * (size_t)QKV_STRIDE;  // QKV_STRIDE floats
    float* out = (float*)d_out;

    qkv_proj   <<<dim3(8, 64, 3), 256, 0, stream>>>(x, wq, bq, nq, wk, bk, nk, wv, bv, nv, qkv);
    attn_flash <<<dim3(32, 64),   256, 0, stream>>>(qkv, go);
    fusion_gemm<<<dim3(8, 8, 8),  256, 0, stream>>>(go, wf, bf, nf, out);
    layernorm_cw<<<dim3(16, 8),   256, 0, stream>>>(out, lng, lnb);
}

// Round 9
// 498.870 us; speedup vs baseline: 3.1431x; 3.1431x over previous
//
#include <hip/hip_runtime.h>
#include <hip/hip_bf16.h>
#include <math.h>

// Problem constants: B=8, C=512, H=W=32 (N=1024), G=8, D=128, Cg=64
#define EPSF 1e-5f
#define SCALE_D 0.08838834764831845f   // 128^-0.5

typedef __attribute__((ext_vector_type(8))) short bf16x8;
typedef __attribute__((ext_vector_type(4))) float f32x4;
#define MFMA16(a, b, c) __builtin_amdgcn_mfma_f32_16x16x32_bf16(a, b, c, 0, 0, 0)

constexpr size_t QT_ELEMS = 64ull * 1024 * 128;   // one bf16 tensor [64 bg][1024][128]
constexpr size_t GO_ELEMS = 8ull * 1024 * 1024;   // go2 bf16 [8 b][1024 n][1024 c]

__device__ __forceinline__ float gelu_exact(float x) {
    return 0.5f * x * (1.0f + erff(x * 0.70710678118654752f));
}

__device__ __forceinline__ unsigned f2bf(float f) {  // RNE fp32 -> bf16 bits
    union { float f; unsigned u; } v; v.f = f;
    unsigned r = v.u + 0x7fff + ((v.u >> 16) & 1);
    return r >> 16;
}
__device__ __forceinline__ unsigned pack2(float a, float b) {
    return f2bf(a) | (f2bf(b) << 16);
}

// ---------------------------------------------------------------------------
// Kernel A: grouped 1x1 conv (qkv proj) + BN(eval) + exact GELU -> bf16
//   z=0 -> qt [bg][n][d] (pre-scaled by D^-0.5), z=1 -> kt [bg][n][d],
//   z=2 -> vv [bg][d][n]
// grid (8 n-tiles, 64 bg, 3), block 256 (16x16), tile 128d x 128n, K=64
// ---------------------------------------------------------------------------
__global__ __launch_bounds__(256) void qkv_proj(
    const float* __restrict__ x,
    const float* __restrict__ wq, const float* __restrict__ bq, const float* __restrict__ nq,
    const float* __restrict__ wk, const float* __restrict__ bk, const float* __restrict__ nk,
    const float* __restrict__ wv, const float* __restrict__ bv, const float* __restrict__ nv,
    unsigned short* __restrict__ qt, unsigned short* __restrict__ kt,
    unsigned short* __restrict__ vv)
{
    __shared__ float ws_t[32][132];   // transposed weight tile [c][d]
    __shared__ float xs[32][128];     // x tile [c][n]

    const int t  = threadIdx.x;
    const int tx = t & 15, ty = t >> 4;
    const int n0 = blockIdx.x * 128;
    const int bg = blockIdx.y;
    const int b  = bg >> 3, g = bg & 7;
    const int z  = blockIdx.z;

    const float* w  = (z == 0) ? wq : (z == 1) ? wk : wv;
    const float* bs = (z == 0) ? bq : (z == 1) ? bk : bv;
    const float* bn = (z == 0) ? nq : (z == 1) ? nk : nv;

    float acc[8][8];
    #pragma unroll
    for (int r = 0; r < 8; ++r)
        #pragma unroll
        for (int jj = 0; jj < 8; ++jj) acc[r][jj] = 0.0f;

    const float* xbase = x + (size_t)(b * 512 + g * 64) * 1024 + n0;
    const float* wbase = w + g * (128 * 64);

    for (int kb = 0; kb < 64; kb += 32) {
        __syncthreads();
        #pragma unroll
        for (int it = 0; it < 16; ++it) {     // w tile: 128 d x 32 c, transposed
            int idx = it * 256 + t;
            int cl = idx & 31, d = idx >> 5;
            ws_t[cl][d] = wbase[d * 64 + kb + cl];
        }
        #pragma unroll
        for (int it = 0; it < 16; ++it) {     // x tile: 32 c x 128 n
            int idx = it * 256 + t;
            int nl = idx & 127, cl = idx >> 7;
            xs[cl][nl] = xbase[(size_t)(kb + cl) * 1024 + nl];
        }
        __syncthreads();
        #pragma unroll
        for (int k = 0; k < 32; ++k) {
            float a[8], bb[8];
            *(float4*)&a[0]  = *(const float4*)&ws_t[k][8 * ty];
            *(float4*)&a[4]  = *(const float4*)&ws_t[k][8 * ty + 4];
            *(float4*)&bb[0] = *(const float4*)&xs[k][8 * tx];
            *(float4*)&bb[4] = *(const float4*)&xs[k][8 * tx + 4];
            #pragma unroll
            for (int r = 0; r < 8; ++r)
                #pragma unroll
                for (int jj = 0; jj < 8; ++jj)
                    acc[r][jj] = fmaf(a[r], bb[jj], acc[r][jj]);
        }
    }

    // BN + GELU in place
    const float* bng = bn + g * 128;
    #pragma unroll
    for (int r = 0; r < 8; ++r) {
        int d = 8 * ty + r;
        float gamma = bng[d];
        float beta  = bng[1024 + d];
        float mean  = bng[2048 + d];
        float var   = bng[3072 + d];
        float sc  = gamma * rsqrtf(var + EPSF);
        float off = (bs[g * 128 + d] - mean) * sc + beta;
        #pragma unroll
        for (int jj = 0; jj < 8; ++jj)
            acc[r][jj] = gelu_exact(fmaf(acc[r][jj], sc, off));
    }

    if (z == 2) {
        // vv: [bg][d][n] bf16, contiguous n
        #pragma unroll
        for (int r = 0; r < 8; ++r) {
            int d = 8 * ty + r;
            uint4 wv4;
            wv4.x = pack2(acc[r][0], acc[r][1]);
            wv4.y = pack2(acc[r][2], acc[r][3]);
            wv4.z = pack2(acc[r][4], acc[r][5]);
            wv4.w = pack2(acc[r][6], acc[r][7]);
            *(uint4*)&vv[((size_t)bg * 128 + d) * 1024 + n0 + 8 * tx] = wv4;
        }
    } else {
        // qt/kt: [bg][n][d] bf16, contiguous d (q pre-scaled)
        const float s = (z == 0) ? SCALE_D : 1.0f;
        unsigned short* base = (z == 0) ? qt : kt;
        #pragma unroll
        for (int jj = 0; jj < 8; ++jj) {
            int n = n0 + 8 * tx + jj;
            uint4 wq4;
            wq4.x = pack2(acc[0][jj] * s, acc[1][jj] * s);
            wq4.y = pack2(acc[2][jj] * s, acc[3][jj] * s);
            wq4.z = pack2(acc[4][jj] * s, acc[5][jj] * s);
            wq4.w = pack2(acc[6][jj] * s, acc[7][jj] * s);
            *(uint4*)&base[((size_t)bg * 1024 + n) * 128 + 8 * ty] = wq4;
        }
    }
}

// ---------------------------------------------------------------------------
// Kernel A2: w_f fp32 [512][1024] -> bf16 (for fusion MFMA A-operand)
// ---------------------------------------------------------------------------
__global__ __launch_bounds__(256) void cvt_wf(
    const float* __restrict__ wf, unsigned short* __restrict__ wfb)
{
    int i = blockIdx.x * 256 + threadIdx.x;   // 65536 threads x 8 elems
    const float4 a = ((const float4*)wf)[i * 2];
    const float4 b = ((const float4*)wf)[i * 2 + 1];
    uint4 o;
    o.x = pack2(a.x, a.y); o.y = pack2(a.z, a.w);
    o.z = pack2(b.x, b.y); o.w = pack2(b.z, b.w);
    ((uint4*)wfb)[i] = o;
}

// ---------------------------------------------------------------------------
// Kernel B: MFMA flash attention.  1024 blocks (16 q-tiles x 64 bg, XCD-
// swizzled), 4 waves/block, each wave owns 16 q rows, KBLK=64 keys/tile.
// Swapped QK^T: S^T = mfma(K,Q) so softmax rescale is lane-uniform (col=q).
// K/V fragments straight from global (L2/L3-resident). P via per-wave LDS.
// No __syncthreads in the whole kernel.
// Output: go2 bf16 [b][n][c=g*128+d]  (fusion B-operand layout)
// ---------------------------------------------------------------------------
__global__ __launch_bounds__(256) void attn_mfma(
    const unsigned short* __restrict__ qt, const unsigned short* __restrict__ kt,
    const unsigned short* __restrict__ vv, unsigned short* __restrict__ go2)
{
    __shared__ unsigned short plds[4][16 * 72];   // per-wave P tile [16 q][72]

    const int t    = threadIdx.x;
    const int wave = t >> 6, lane = t & 63;
    const int lr   = lane & 15;       // MFMA col index (= q), also A-row index
    const int lh   = lane >> 4;       // 0..3: k-chunk / C-row group

    // XCD-bijective swizzle: XCD i gets 8 consecutive bg (K/V stay in its L2)
    const int blk     = blockIdx.x;
    const int logical = (blk & 7) * 128 + (blk >> 3);
    const int bg      = logical >> 4;
    const int qtile   = logical & 15;
    const int q0      = qtile * 64 + wave * 16;

    const unsigned short* qtb = qt + ((size_t)bg * 1024 + q0) * 128;
    const unsigned short* ktb = kt + (size_t)bg * 1024 * 128;
    const unsigned short* vb  = vv + (size_t)bg * 128 * 1024;
    unsigned short* pl = &plds[wave][0];

    // Q B-fragments (invariant over K-tiles): B[k=d][col=q]
    bf16x8 qf[4];
    #pragma unroll
    for (int kk = 0; kk < 4; ++kk)
        qf[kk] = *(const bf16x8*)(qtb + lr * 128 + kk * 32 + lh * 8);

    f32x4 Ot[8];                      // O^T[d=dt*16+lh*4+r][q=lr]
    #pragma unroll
    for (int dt = 0; dt < 8; ++dt) Ot[dt] = (f32x4){0.f, 0.f, 0.f, 0.f};
    float mrun = -INFINITY, lrun = 0.0f;

    for (int ktile = 0; ktile < 16; ++ktile) {
        const int m0 = ktile * 64;
        const unsigned short* kbase = ktb + (size_t)m0 * 128;

        // ---- S^T = K * Q : 4 m-tiles x 4 k-steps ----
        f32x4 st[4];
        #pragma unroll
        for (int mt = 0; mt < 4; ++mt) st[mt] = (f32x4){0.f, 0.f, 0.f, 0.f};
        #pragma unroll
        for (int kk = 0; kk < 4; ++kk) {
            #pragma unroll
            for (int mt = 0; mt < 4; ++mt) {
                bf16x8 af = *(const bf16x8*)(kbase + (size_t)(mt * 16 + lr) * 128 + kk * 32 + lh * 8);
                st[mt] = MFMA16(af, qf[kk], st[mt]);
            }
        }

        // ---- online softmax (per lane: 16 keys of column q=lr) ----
        float tm = -INFINITY;
        #pragma unroll
        for (int mt = 0; mt < 4; ++mt)
            #pragma unroll
            for (int r = 0; r < 4; ++r) tm = fmaxf(tm, st[mt][r]);
        tm = fmaxf(tm, __shfl_xor(tm, 16));
        tm = fmaxf(tm, __shfl_xor(tm, 32));
        float nm = fmaxf(mrun, tm);
        float rf = __expf(mrun - nm);
        float ts = 0.0f;
        #pragma unroll
        for (int mt = 0; mt < 4; ++mt)
            #pragma unroll
            for (int r = 0; r < 4; ++r) {
                float p = __expf(st[mt][r] - nm);
                st[mt][r] = p;
                ts += p;
            }
        ts += __shfl_xor(ts, 16);
        ts += __shfl_xor(ts, 32);
        lrun = lrun * rf + ts;
        mrun = nm;
        #pragma unroll
        for (int dt = 0; dt < 8; ++dt) Ot[dt] *= rf;

        // ---- P -> bf16 -> per-wave LDS [q=lr][m] ----
        #pragma unroll
        for (int mt = 0; mt < 4; ++mt) {
            uint2 pw;
            pw.x = pack2(st[mt][0], st[mt][1]);
            pw.y = pack2(st[mt][2], st[mt][3]);
            *(uint2*)&pl[lr * 72 + mt * 16 + lh * 4] = pw;
        }

        // ---- O^T += V * P^T : 8 d-tiles x 2 k-steps ----
        #pragma unroll
        for (int ks = 0; ks < 2; ++ks) {
            bf16x8 pf = *(const bf16x8*)&pl[lr * 72 + ks * 32 + lh * 8];
            #pragma unroll
            for (int dt = 0; dt < 8; ++dt) {
                bf16x8 vf = *(const bf16x8*)(vb + (size_t)(dt * 16 + lr) * 1024 + m0 + ks * 32 + lh * 8);
                Ot[dt] = MFMA16(vf, pf, Ot[dt]);
            }
        }
    }

    // ---- normalize + store bf16 go2[b][n=q0+lr][c = g*128 + dt*16 + lh*4 + r] ----
    const float inv = 1.0f / lrun;
    const int b = bg >> 3, g = bg & 7;
    unsigned short* gob = go2 + ((size_t)(b * 1024) + q0 + lr) * 1024 + g * 128 + lh * 4;
    #pragma unroll
    for (int dt = 0; dt < 8; ++dt) {
        uint2 pw;
        pw.x = pack2(Ot[dt][0] * inv, Ot[dt][1] * inv);
        pw.y = pack2(Ot[dt][2] * inv, Ot[dt][3] * inv);
        *(uint2*)&gob[dt * 16] = pw;
    }
}

// ---------------------------------------------------------------------------
// Kernel C: fusion 1x1 conv (1024 -> 512) via MFMA + BN(eval) + GELU -> d_out
// C[co][n] = sum_ci W[co][ci] * go2[b][n][ci].  Tile 64co x 128n, 4 waves
// (each 64co x 32n), K=1024.  A-frag = wfb (natural layout), B-frag = go2.
// grid (8 n-tiles, 8 co-tiles, 8 b) = 512 blocks.
// ---------------------------------------------------------------------------
__global__ __launch_bounds__(256) void fusion_mfma(
    const unsigned short* __restrict__ go2, const unsigned short* __restrict__ wfb,
    const float* __restrict__ bf, const float* __restrict__ bnf,
    float* __restrict__ y)
{
    const int t    = threadIdx.x;
    const int wave = t >> 6, lane = t & 63;
    const int lr   = lane & 15;
    const int lh   = lane >> 4;

    const int n0  = blockIdx.x * 128 + wave * 32;
    const int co0 = blockIdx.y * 64;
    const int b   = blockIdx.z;

    const unsigned short* gb = go2 + (size_t)b * 1024 * 1024;

    f32x4 acc[4][2];   // [mr: co frag][mc: n frag]
    #pragma unroll
    for (int mr = 0; mr < 4; ++mr)
        #pragma unroll
        for (int mc = 0; mc < 2; ++mc) acc[mr][mc] = (f32x4){0.f, 0.f, 0.f, 0.f};

    #pragma unroll 4
    for (int k0 = 0; k0 < 1024; k0 += 32) {
        bf16x8 af[4], bq[2];
        #pragma unroll
        for (int mr = 0; mr < 4; ++mr)
            af[mr] = *(const bf16x8*)&wfb[(size_t)(co0 + mr * 16 + lr) * 1024 + k0 + lh * 8];
        #pragma unroll
        for (int mc = 0; mc < 2; ++mc)
            bq[mc] = *(const bf16x8*)&gb[(size_t)(n0 + mc * 16 + lr) * 1024 + k0 + lh * 8];
        #pragma unroll
        for (int mr = 0; mr < 4; ++mr)
            #pragma unroll
            for (int mc = 0; mc < 2; ++mc)
                acc[mr][mc] = MFMA16(af[mr], bq[mc], acc[mr][mc]);
    }

    // epilogue: BN + GELU, store fp32. C row = co (co0+mr*16+lh*4+r), col = n.
    float* yb = y + (size_t)b * 512 * 1024;
    #pragma unroll
    for (int mr = 0; mr < 4; ++mr) {
        #pragma unroll
        for (int r = 0; r < 4; ++r) {
            int co = co0 + mr * 16 + lh * 4 + r;
            float sc  = bnf[co] * rsqrtf(bnf[1536 + co] + EPSF);
            float off = (bf[co] - bnf[1024 + co]) * sc + bnf[512 + co];
            #pragma unroll
            for (int mc = 0; mc < 2; ++mc) {
                int n = n0 + mc * 16 + lr;
                yb[(size_t)co * 1024 + n] = gelu_exact(fmaf(acc[mr][mc][r], sc, off));
            }
        }
    }
}

// ---------------------------------------------------------------------------
// Kernel D: LayerNorm over channel dim, in-place on d_out
// ---------------------------------------------------------------------------
__global__ __launch_bounds__(256) void layernorm_cw(
    float* __restrict__ y, const float* __restrict__ lng, const float* __restrict__ lnb)
{
    __shared__ float s1[4][64];
    __shared__ float s2[4][64];
    const int t = threadIdx.x;
    const int cl = t & 63, cg = t >> 6;
    const int col = blockIdx.x * 64 + cl;
    const int b   = blockIdx.y;
    float* yb = y + (size_t)b * 512 * 1024 + col;

    float sum = 0.0f, sq = 0.0f;
    for (int c = cg * 128; c < cg * 128 + 128; ++c) {
        float v = yb[(size_t)c * 1024];
        sum += v; sq = fmaf(v, v, sq);
    }
    s1[cg][cl] = sum; s2[cg][cl] = sq;
    __syncthreads();
    float st = s1[0][cl] + s1[1][cl] + s1[2][cl] + s1[3][cl];
    float qt = s2[0][cl] + s2[1][cl] + s2[2][cl] + s2[3][cl];
    float mean = st * (1.0f / 512.0f);
    float var  = qt * (1.0f / 512.0f) - mean * mean;
    float rstd = rsqrtf(var + EPSF);
    for (int c = cg * 128; c < cg * 128 + 128; ++c) {
        float v = yb[(size_t)c * 1024];
        yb[(size_t)c * 1024] = (v - mean) * rstd * lng[c] + lnb[c];
    }
}

// ---------------------------------------------------------------------------
extern "C" void kernel_launch(void* const* d_in, const int* in_sizes, int n_in,
                              void* d_out, int out_size, void* d_ws, size_t ws_size,
                              hipStream_t stream) {
    const float* x   = (const float*)d_in[0];
    const float* wq  = (const float*)d_in[1];
    const float* bq  = (const float*)d_in[2];
    const float* nq  = (const float*)d_in[3];
    const float* wk  = (const float*)d_in[4];
    const float* bk  = (const float*)d_in[5];
    const float* nk  = (const float*)d_in[6];
    const float* wv  = (const float*)d_in[7];
    const float* bv  = (const float*)d_in[8];
    const float* nv  = (const float*)d_in[9];
    const float* wf  = (const float*)d_in[10];
    const float* bf  = (const float*)d_in[11];
    const float* nf  = (const float*)d_in[12];
    const float* lng = (const float*)d_in[13];
    const float* lnb = (const float*)d_in[14];

    unsigned short* qt  = (unsigned short*)d_ws;     // bf16 [64][1024][128], pre-scaled
    unsigned short* kt  = qt + QT_ELEMS;             // bf16 [64][1024][128]
    unsigned short* vv  = kt + QT_ELEMS;             // bf16 [64][128][1024]
    unsigned short* go2 = vv + QT_ELEMS;             // bf16 [8][1024 n][1024 c]
    unsigned short* wfb = go2 + GO_ELEMS;            // bf16 [512][1024]
    float* out = (float*)d_out;

    qkv_proj    <<<dim3(8, 64, 3), 256, 0, stream>>>(x, wq, bq, nq, wk, bk, nk, wv, bv, nv, qt, kt, vv);
    cvt_wf      <<<dim3(256),      256, 0, stream>>>(wf, wfb);
    attn_mfma   <<<dim3(1024),     256, 0, stream>>>(qt, kt, vv, go2);
    fusion_mfma <<<dim3(8, 8, 8),  256, 0, stream>>>(go2, wfb, bf, nf, out);
    layernorm_cw<<<dim3(16, 8),    256, 0, stream>>>(out, lng, lnb);
}

// Round 14
// 279.305 us; speedup vs baseline: 5.6140x; 1.7861x over previous
//
#include <hip/hip_runtime.h>
#include <hip/hip_bf16.h>
#include <math.h>

// Problem constants: B=8, C=512, H=W=32 (N=1024), G=8, D=128, Cg=64
#define EPSF 1e-5f
#define SCALE_D 0.08838834764831845f   // 128^-0.5

typedef __attribute__((ext_vector_type(8))) short bf16x8;
typedef __attribute__((ext_vector_type(4))) float f32x4;
#define MFMA16(a, b, c) __builtin_amdgcn_mfma_f32_16x16x32_bf16(a, b, c, 0, 0, 0)

constexpr size_t QT_ELEMS = 64ull * 1024 * 128;   // one bf16 tensor [64 bg][1024][128]
constexpr size_t GO_ELEMS = 8ull * 1024 * 1024;   // go2 bf16 [8 b][1024 n][1024 c]

__device__ __forceinline__ float gelu_exact(float x) {
    return 0.5f * x * (1.0f + erff(x * 0.70710678118654752f));
}

__device__ __forceinline__ unsigned f2bf(float f) {  // RNE fp32 -> bf16 bits
    union { float f; unsigned u; } v; v.f = f;
    unsigned r = v.u + 0x7fff + ((v.u >> 16) & 1);
    return r >> 16;
}
__device__ __forceinline__ unsigned pack2(float a, float b) {
    return f2bf(a) | (f2bf(b) << 16);
}

// ---------------------------------------------------------------------------
// Kernel A: grouped 1x1 conv (qkv proj) + BN(eval) + exact GELU -> bf16
//   z=0 -> qt [bg][n][d] (pre-scaled by D^-0.5), z=1 -> kt [bg][n][d],
//   z=2 -> vv [bg][d][n]
// grid (8 n-tiles, 64 bg, 3), block 256 (16x16), tile 128d x 128n, K=64
// ---------------------------------------------------------------------------
__global__ __launch_bounds__(256) void qkv_proj(
    const float* __restrict__ x,
    const float* __restrict__ wq, const float* __restrict__ bq, const float* __restrict__ nq,
    const float* __restrict__ wk, const float* __restrict__ bk, const float* __restrict__ nk,
    const float* __restrict__ wv, const float* __restrict__ bv, const float* __restrict__ nv,
    unsigned short* __restrict__ qt, unsigned short* __restrict__ kt,
    unsigned short* __restrict__ vv)
{
    __shared__ float ws_t[32][132];   // transposed weight tile [c][d]
    __shared__ float xs[32][128];     // x tile [c][n]

    const int t  = threadIdx.x;
    const int tx = t & 15, ty = t >> 4;
    const int n0 = blockIdx.x * 128;
    const int bg = blockIdx.y;
    const int b  = bg >> 3, g = bg & 7;
    const int z  = blockIdx.z;

    const float* w  = (z == 0) ? wq : (z == 1) ? wk : wv;
    const float* bs = (z == 0) ? bq : (z == 1) ? bk : bv;
    const float* bn = (z == 0) ? nq : (z == 1) ? nk : nv;

    float acc[8][8];
    #pragma unroll
    for (int r = 0; r < 8; ++r)
        #pragma unroll
        for (int jj = 0; jj < 8; ++jj) acc[r][jj] = 0.0f;

    const float* xbase = x + (size_t)(b * 512 + g * 64) * 1024 + n0;
    const float* wbase = w + g * (128 * 64);

    for (int kb = 0; kb < 64; kb += 32) {
        __syncthreads();
        #pragma unroll
        for (int it = 0; it < 16; ++it) {     // w tile: 128 d x 32 c, transposed
            int idx = it * 256 + t;
            int cl = idx & 31, d = idx >> 5;
            ws_t[cl][d] = wbase[d * 64 + kb + cl];
        }
        #pragma unroll
        for (int it = 0; it < 16; ++it) {     // x tile: 32 c x 128 n
            int idx = it * 256 + t;
            int nl = idx & 127, cl = idx >> 7;
            xs[cl][nl] = xbase[(size_t)(kb + cl) * 1024 + nl];
        }
        __syncthreads();
        #pragma unroll
        for (int k = 0; k < 32; ++k) {
            float a[8], bb[8];
            *(float4*)&a[0]  = *(const float4*)&ws_t[k][8 * ty];
            *(float4*)&a[4]  = *(const float4*)&ws_t[k][8 * ty + 4];
            *(float4*)&bb[0] = *(const float4*)&xs[k][8 * tx];
            *(float4*)&bb[4] = *(const float4*)&xs[k][8 * tx + 4];
            #pragma unroll
            for (int r = 0; r < 8; ++r)
                #pragma unroll
                for (int jj = 0; jj < 8; ++jj)
                    acc[r][jj] = fmaf(a[r], bb[jj], acc[r][jj]);
        }
    }

    // BN + GELU in place
    const float* bng = bn + g * 128;
    #pragma unroll
    for (int r = 0; r < 8; ++r) {
        int d = 8 * ty + r;
        float gamma = bng[d];
        float beta  = bng[1024 + d];
        float mean  = bng[2048 + d];
        float var   = bng[3072 + d];
        float sc  = gamma * rsqrtf(var + EPSF);
        float off = (bs[g * 128 + d] - mean) * sc + beta;
        #pragma unroll
        for (int jj = 0; jj < 8; ++jj)
            acc[r][jj] = gelu_exact(fmaf(acc[r][jj], sc, off));
    }

    if (z == 2) {
        // vv: [bg][d][n] bf16, contiguous n
        #pragma unroll
        for (int r = 0; r < 8; ++r) {
            int d = 8 * ty + r;
            uint4 wv4;
            wv4.x = pack2(acc[r][0], acc[r][1]);
            wv4.y = pack2(acc[r][2], acc[r][3]);
            wv4.z = pack2(acc[r][4], acc[r][5]);
            wv4.w = pack2(acc[r][6], acc[r][7]);
            *(uint4*)&vv[((size_t)bg * 128 + d) * 1024 + n0 + 8 * tx] = wv4;
        }
    } else {
        // qt/kt: [bg][n][d] bf16, contiguous d (q pre-scaled)
        const float s = (z == 0) ? SCALE_D : 1.0f;
        unsigned short* base = (z == 0) ? qt : kt;
        #pragma unroll
        for (int jj = 0; jj < 8; ++jj) {
            int n = n0 + 8 * tx + jj;
            uint4 wq4;
            wq4.x = pack2(acc[0][jj] * s, acc[1][jj] * s);
            wq4.y = pack2(acc[2][jj] * s, acc[3][jj] * s);
            wq4.z = pack2(acc[4][jj] * s, acc[5][jj] * s);
            wq4.w = pack2(acc[6][jj] * s, acc[7][jj] * s);
            *(uint4*)&base[((size_t)bg * 1024 + n) * 128 + 8 * ty] = wq4;
        }
    }
}

// ---------------------------------------------------------------------------
// Kernel A2: w_f fp32 [512][1024] -> bf16 (for fusion MFMA A-operand)
// ---------------------------------------------------------------------------
__global__ __launch_bounds__(256) void cvt_wf(
    const float* __restrict__ wf, unsigned short* __restrict__ wfb)
{
    int i = blockIdx.x * 256 + threadIdx.x;   // 65536 threads x 8 elems
    const float4 a = ((const float4*)wf)[i * 2];
    const float4 b = ((const float4*)wf)[i * 2 + 1];
    uint4 o;
    o.x = pack2(a.x, a.y); o.y = pack2(a.z, a.w);
    o.z = pack2(b.x, b.y); o.w = pack2(b.z, b.w);
    ((uint4*)wfb)[i] = o;
}

// ---------------------------------------------------------------------------
// Kernel B: MFMA flash attention, LDS-staged K/V with register prefetch.
// 1024 blocks (16 q-tiles x 64 bg, XCD-swizzled), 4 waves/block.
// Per K-tile (64 keys): all 4 waves share one staged K tile (64x128 bf16,
// 16KB) and one V tile (128x64 bf16, 16KB), XOR-swizzled byte^((row&7)<<4)
// to kill the 16-way ds_read_b128 bank conflict (Guideline 4).
// Pipeline (T14): regs->LDS, barrier, issue NEXT tile global->regs (latency
// hides under compute), compute QK/softmax/PV from LDS.
// Output: go2 bf16 [b][n][c=g*128+d]  (fusion B-operand layout)
// ---------------------------------------------------------------------------
__global__ __launch_bounds__(256) void attn_mfma(
    const unsigned short* __restrict__ qt, const unsigned short* __restrict__ kt,
    const unsigned short* __restrict__ vv, unsigned short* __restrict__ go2)
{
    __shared__ unsigned short klds[64 * 128];     // K tile, 256B rows, swizzled
    __shared__ unsigned short vlds[128 * 64];     // V tile, 128B rows, swizzled
    __shared__ unsigned short plds[4][16 * 72];   // per-wave P tile [16 q][72]

    const int t    = threadIdx.x;
    const int wave = t >> 6, lane = t & 63;
    const int lr   = lane & 15;       // MFMA col index (= q), also A-row index
    const int lh   = lane >> 4;       // 0..3: k-chunk / C-row group
    const int swz  = (lr & 7) << 4;   // row-XOR for swizzled LDS reads

    // XCD-bijective swizzle: XCD i gets 8 consecutive bg (K/V stay in its L2)
    const int blk     = blockIdx.x;
    const int logical = (blk & 7) * 128 + (blk >> 3);
    const int bg      = logical >> 4;
    const int qtile   = logical & 15;
    const int q0      = qtile * 64 + wave * 16;

    const unsigned short* qtb = qt + ((size_t)bg * 1024 + q0) * 128;
    const unsigned short* ktb = kt + (size_t)bg * 1024 * 128;
    const unsigned short* vb  = vv + (size_t)bg * 128 * 1024;
    unsigned short* pl = &plds[wave][0];

    // Q B-fragments (invariant over K-tiles): B[k=d][col=q]
    bf16x8 qf[4];
    #pragma unroll
    for (int kk = 0; kk < 4; ++kk)
        qf[kk] = *(const bf16x8*)(qtb + lr * 128 + kk * 32 + lh * 8);

    f32x4 Ot[8];                      // O^T[d=dt*16+lh*4+r][q=lr]
    #pragma unroll
    for (int dt = 0; dt < 8; ++dt) Ot[dt] = (f32x4){0.f, 0.f, 0.f, 0.f};
    float mrun = -INFINITY, lrun = 0.0f;

    // ---- prologue: stage tile 0 into regs (K: 4x16B, V: 4x16B per thread) ----
    uint4 kst0, kst1, kst2, kst3, vst0, vst1, vst2, vst3;
    {
        #define LOADK(i, dst) { int idx = i * 256 + t; \
            dst = *(const uint4*)(ktb + (size_t)(idx >> 4) * 128 + (idx & 15) * 8); }
        #define LOADV(i, dst) { int idx = i * 256 + t; \
            dst = *(const uint4*)(vb + (size_t)(idx >> 3) * 1024 + (idx & 7) * 8); }
        LOADK(0, kst0) LOADK(1, kst1) LOADK(2, kst2) LOADK(3, kst3)
        LOADV(0, vst0) LOADV(1, vst1) LOADV(2, vst2) LOADV(3, vst3)
        #undef LOADK
        #undef LOADV
    }

    for (int ktile = 0; ktile < 16; ++ktile) {
        __syncthreads();   // all waves done reading LDS tile ktile-1
        // ---- regs -> LDS (swizzled) ----
        {
            #define STOREK(i, src) { int idx = i * 256 + t; int row = idx >> 4; \
                *(uint4*)((char*)klds + row * 256 + (((idx & 15) * 16) ^ ((row & 7) << 4))) = src; }
            #define STOREV(i, src) { int idx = i * 256 + t; int row = idx >> 3; \
                *(uint4*)((char*)vlds + row * 128 + (((idx & 7) * 16) ^ ((row & 7) << 4))) = src; }
            STOREK(0, kst0) STOREK(1, kst1) STOREK(2, kst2) STOREK(3, kst3)
            STOREV(0, vst0) STOREV(1, vst1) STOREV(2, vst2) STOREV(3, vst3)
            #undef STOREK
            #undef STOREV
        }
        __syncthreads();   // LDS tile ready

        // ---- issue NEXT tile loads (overlap with compute below) ----
        if (ktile < 15) {
            const int m1 = (ktile + 1) * 64;
            #define LOADK(i, dst) { int idx = i * 256 + t; \
                dst = *(const uint4*)(ktb + (size_t)(m1 + (idx >> 4)) * 128 + (idx & 15) * 8); }
            #define LOADV(i, dst) { int idx = i * 256 + t; \
                dst = *(const uint4*)(vb + (size_t)(idx >> 3) * 1024 + m1 + (idx & 7) * 8); }
            LOADK(0, kst0) LOADK(1, kst1) LOADK(2, kst2) LOADK(3, kst3)
            LOADV(0, vst0) LOADV(1, vst1) LOADV(2, vst2) LOADV(3, vst3)
            #undef LOADK
            #undef LOADV
        }

        // ---- S^T = K * Q : 4 m-tiles x 4 k-steps, K from LDS ----
        f32x4 st[4];
        #pragma unroll
        for (int mt = 0; mt < 4; ++mt) st[mt] = (f32x4){0.f, 0.f, 0.f, 0.f};
        #pragma unroll
        for (int kk = 0; kk < 4; ++kk) {
            #pragma unroll
            for (int mt = 0; mt < 4; ++mt) {
                const int row = mt * 16 + lr;
                bf16x8 af = *(const bf16x8*)((const char*)klds + row * 256 + ((kk * 64 + lh * 16) ^ swz));
                st[mt] = MFMA16(af, qf[kk], st[mt]);
            }
        }

        // ---- online softmax (per lane: 16 keys of column q=lr) ----
        float tm = -INFINITY;
        #pragma unroll
        for (int mt = 0; mt < 4; ++mt)
            #pragma unroll
            for (int r = 0; r < 4; ++r) tm = fmaxf(tm, st[mt][r]);
        tm = fmaxf(tm, __shfl_xor(tm, 16));
        tm = fmaxf(tm, __shfl_xor(tm, 32));
        float nm = fmaxf(mrun, tm);
        float rf = __expf(mrun - nm);
        float ts = 0.0f;
        #pragma unroll
        for (int mt = 0; mt < 4; ++mt)
            #pragma unroll
            for (int r = 0; r < 4; ++r) {
                float p = __expf(st[mt][r] - nm);
                st[mt][r] = p;
                ts += p;
            }
        ts += __shfl_xor(ts, 16);
        ts += __shfl_xor(ts, 32);
        lrun = lrun * rf + ts;
        mrun = nm;
        #pragma unroll
        for (int dt = 0; dt < 8; ++dt) Ot[dt] *= rf;

        // ---- P -> bf16 -> per-wave LDS [q=lr][m] ----
        #pragma unroll
        for (int mt = 0; mt < 4; ++mt) {
            uint2 pw;
            pw.x = pack2(st[mt][0], st[mt][1]);
            pw.y = pack2(st[mt][2], st[mt][3]);
            *(uint2*)&pl[lr * 72 + mt * 16 + lh * 4] = pw;
        }

        // ---- O^T += V * P^T : 8 d-tiles x 2 k-steps, V from LDS ----
        #pragma unroll
        for (int ks = 0; ks < 2; ++ks) {
            bf16x8 pf = *(const bf16x8*)&pl[lr * 72 + ks * 32 + lh * 8];
            #pragma unroll
            for (int dt = 0; dt < 8; ++dt) {
                const int row = dt * 16 + lr;
                bf16x8 vf = *(const bf16x8*)((const char*)vlds + row * 128 + ((ks * 64 + lh * 16) ^ swz));
                Ot[dt] = MFMA16(vf, pf, Ot[dt]);
            }
        }
    }

    // ---- normalize + store bf16 go2[b][n=q0+lr][c = g*128 + dt*16 + lh*4 + r] ----
    const float inv = 1.0f / lrun;
    const int b = bg >> 3, g = bg & 7;
    unsigned short* gob = go2 + ((size_t)(b * 1024) + q0 + lr) * 1024 + g * 128 + lh * 4;
    #pragma unroll
    for (int dt = 0; dt < 8; ++dt) {
        uint2 pw;
        pw.x = pack2(Ot[dt][0] * inv, Ot[dt][1] * inv);
        pw.y = pack2(Ot[dt][2] * inv, Ot[dt][3] * inv);
        *(uint2*)&gob[dt * 16] = pw;
    }
}

// ---------------------------------------------------------------------------
// Kernel C: fusion 1x1 conv (1024 -> 512) via MFMA + BN(eval) + GELU -> d_out
// C[co][n] = sum_ci W[co][ci] * go2[b][n][ci].  Tile 64co x 128n, 4 waves,
// K=1024 in 16 chunks of 64.  Same LDS-stage + XOR-swizzle + reg-prefetch
// pattern as attn_mfma (numerics-identical to unstaged version).
// LDS: wlds [64co][64k] 8KB + glds [128n][64k] 16KB.
// grid (8 n-tiles, 8 co-tiles, 8 b) = 512 blocks.
// ---------------------------------------------------------------------------
__global__ __launch_bounds__(256) void fusion_mfma(
    const unsigned short* __restrict__ go2, const unsigned short* __restrict__ wfb,
    const float* __restrict__ bf, const float* __restrict__ bnf,
    float* __restrict__ y)
{
    __shared__ unsigned short wlds[64 * 64];    // [co][k], 128B rows, swizzled
    __shared__ unsigned short glds[128 * 64];   // [n][k],  128B rows, swizzled

    const int t    = threadIdx.x;
    const int wave = t >> 6, lane = t & 63;
    const int lr   = lane & 15;
    const int lh   = lane >> 4;
    const int swz  = (lr & 7) << 4;

    const int n0b = blockIdx.x * 128;
    const int co0 = blockIdx.y * 64;
    const int b   = blockIdx.z;
    const int n0  = n0b + wave * 32;

    const unsigned short* gb = go2 + (size_t)b * 1024 * 1024 + (size_t)n0b * 1024;
    const unsigned short* wb = wfb + (size_t)co0 * 1024;

    f32x4 acc[4][2];   // [mr: co frag][mc: n frag]
    #pragma unroll
    for (int mr = 0; mr < 4; ++mr)
        #pragma unroll
        for (int mc = 0; mc < 2; ++mc) acc[mr][mc] = (f32x4){0.f, 0.f, 0.f, 0.f};

    // ---- prologue: stage chunk 0 into regs (W: 2x16B, G: 4x16B per thread) ----
    uint4 wst0, wst1, gst0, gst1, gst2, gst3;
    {
        #define LOADW(i, dst) { int idx = i * 256 + t; \
            dst = *(const uint4*)(wb + (size_t)(idx >> 3) * 1024 + (idx & 7) * 8); }
        #define LOADG(i, dst) { int idx = i * 256 + t; \
            dst = *(const uint4*)(gb + (size_t)(idx >> 3) * 1024 + (idx & 7) * 8); }
        LOADW(0, wst0) LOADW(1, wst1)
        LOADG(0, gst0) LOADG(1, gst1) LOADG(2, gst2) LOADG(3, gst3)
        #undef LOADW
        #undef LOADG
    }

    for (int kc = 0; kc < 16; ++kc) {
        __syncthreads();
        // ---- regs -> LDS (swizzled) ----
        {
            #define STOREW(i, src) { int idx = i * 256 + t; int row = idx >> 3; \
                *(uint4*)((char*)wlds + row * 128 + (((idx & 7) * 16) ^ ((row & 7) << 4))) = src; }
            #define STOREG(i, src) { int idx = i * 256 + t; int row = idx >> 3; \
                *(uint4*)((char*)glds + row * 128 + (((idx & 7) * 16) ^ ((row & 7) << 4))) = src; }
            STOREW(0, wst0) STOREW(1, wst1)
            STOREG(0, gst0) STOREG(1, gst1) STOREG(2, gst2) STOREG(3, gst3)
            #undef STOREW
            #undef STOREG
        }
        __syncthreads();

        // ---- issue NEXT chunk loads ----
        if (kc < 15) {
            const int k1 = (kc + 1) * 64;
            #define LOADW(i, dst) { int idx = i * 256 + t; \
                dst = *(const uint4*)(wb + (size_t)(idx >> 3) * 1024 + k1 + (idx & 7) * 8); }
            #define LOADG(i, dst) { int idx = i * 256 + t; \
                dst = *(const uint4*)(gb + (size_t)(idx >> 3) * 1024 + k1 + (idx & 7) * 8); }
            LOADW(0, wst0) LOADW(1, wst1)
            LOADG(0, gst0) LOADG(1, gst1) LOADG(2, gst2) LOADG(3, gst3)
            #undef LOADW
            #undef LOADG
        }

        // ---- compute: 2 k-steps of 32, fragments from LDS ----
        #pragma unroll
        for (int s = 0; s < 2; ++s) {
            bf16x8 af[4], bq[2];
            #pragma unroll
            for (int mr = 0; mr < 4; ++mr) {
                const int row = mr * 16 + lr;
                af[mr] = *(const bf16x8*)((const char*)wlds + row * 128 + ((s * 64 + lh * 16) ^ swz));
            }
            #pragma unroll
            for (int mc = 0; mc < 2; ++mc) {
                const int row = wave * 32 + mc * 16 + lr;
                bq[mc] = *(const bf16x8*)((const char*)glds + row * 128 + ((s * 64 + lh * 16) ^ swz));
            }
            #pragma unroll
            for (int mr = 0; mr < 4; ++mr)
                #pragma unroll
                for (int mc = 0; mc < 2; ++mc)
                    acc[mr][mc] = MFMA16(af[mr], bq[mc], acc[mr][mc]);
        }
    }

    // epilogue: BN + GELU, store fp32. C row = co (co0+mr*16+lh*4+r), col = n.
    float* yb = y + (size_t)b * 512 * 1024;
    #pragma unroll
    for (int mr = 0; mr < 4; ++mr) {
        #pragma unroll
        for (int r = 0; r < 4; ++r) {
            int co = co0 + mr * 16 + lh * 4 + r;
            float sc  = bnf[co] * rsqrtf(bnf[1536 + co] + EPSF);
            float off = (bf[co] - bnf[1024 + co]) * sc + bnf[512 + co];
            #pragma unroll
            for (int mc = 0; mc < 2; ++mc) {
                int n = n0 + mc * 16 + lr;
                yb[(size_t)co * 1024 + n] = gelu_exact(fmaf(acc[mr][mc][r], sc, off));
            }
        }
    }
}

// ---------------------------------------------------------------------------
// Kernel D: LayerNorm over channel dim, in-place on d_out
// ---------------------------------------------------------------------------
__global__ __launch_bounds__(256) void layernorm_cw(
    float* __restrict__ y, const float* __restrict__ lng, const float* __restrict__ lnb)
{
    __shared__ float s1[4][64];
    __shared__ float s2[4][64];
    const int t = threadIdx.x;
    const int cl = t & 63, cg = t >> 6;
    const int col = blockIdx.x * 64 + cl;
    const int b   = blockIdx.y;
    float* yb = y + (size_t)b * 512 * 1024 + col;

    float sum = 0.0f, sq = 0.0f;
    for (int c = cg * 128; c < cg * 128 + 128; ++c) {
        float v = yb[(size_t)c * 1024];
        sum += v; sq = fmaf(v, v, sq);
    }
    s1[cg][cl] = sum; s2[cg][cl] = sq;
    __syncthreads();
    float st = s1[0][cl] + s1[1][cl] + s1[2][cl] + s1[3][cl];
    float qt = s2[0][cl] + s2[1][cl] + s2[2][cl] + s2[3][cl];
    float mean = st * (1.0f / 512.0f);
    float var  = qt * (1.0f / 512.0f) - mean * mean;
    float rstd = rsqrtf(var + EPSF);
    for (int c = cg * 128; c < cg * 128 + 128; ++c) {
        float v = yb[(size_t)c * 1024];
        yb[(size_t)c * 1024] = (v - mean) * rstd * lng[c] + lnb[c];
    }
}

// ---------------------------------------------------------------------------
extern "C" void kernel_launch(void* const* d_in, const int* in_sizes, int n_in,
                              void* d_out, int out_size, void* d_ws, size_t ws_size,
                              hipStream_t stream) {
    const float* x   = (const float*)d_in[0];
    const float* wq  = (const float*)d_in[1];
    const float* bq  = (const float*)d_in[2];
    const float* nq  = (const float*)d_in[3];
    const float* wk  = (const float*)d_in[4];
    const float* bk  = (const float*)d_in[5];
    const float* nk  = (const float*)d_in[6];
    const float* wv  = (const float*)d_in[7];
    const float* bv  = (const float*)d_in[8];
    const float* nv  = (const float*)d_in[9];
    const float* wf  = (const float*)d_in[10];
    const float* bf  = (const float*)d_in[11];
    const float* nf  = (const float*)d_in[12];
    const float* lng = (const float*)d_in[13];
    const float* lnb = (const float*)d_in[14];

    unsigned short* qt  = (unsigned short*)d_ws;     // bf16 [64][1024][128], pre-scaled
    unsigned short* kt  = qt + QT_ELEMS;             // bf16 [64][1024][128]
    unsigned short* vv  = kt + QT_ELEMS;             // bf16 [64][128][1024]
    unsigned short* go2 = vv + QT_ELEMS;             // bf16 [8][1024 n][1024 c]
    unsigned short* wfb = go2 + GO_ELEMS;            // bf16 [512][1024]
    float* out = (float*)d_out;

    qkv_proj    <<<dim3(8, 64, 3), 256, 0, stream>>>(x, wq, bq, nq, wk, bk, nk, wv, bv, nv, qt, kt, vv);
    cvt_wf      <<<dim3(256),      256, 0, stream>>>(wf, wfb);
    attn_mfma   <<<dim3(1024),     256, 0, stream>>>(qt, kt, vv, go2);
    fusion_mfma <<<dim3(8, 8, 8),  256, 0, stream>>>(go2, wfb, bf, nf, out);
    layernorm_cw<<<dim3(16, 8),    256, 0, stream>>>(out, lng, lnb);
}